// Round 1
// baseline (2042.184 us; speedup 1.0000x reference)
//
#include <hip/hip_runtime.h>

#define N_NODES 100000
#define N_EDGES 1600000
#define HID 256

constexpr int SCAN_CHUNK = 1024;
constexpr int NBLK = (N_NODES + SCAN_CHUNK - 1) / SCAN_CHUNK; // 98

// ---------------- CSR build ----------------
__global__ void k_count(const int* __restrict__ dst, int* __restrict__ deg) {
    int e = blockIdx.x * 256 + threadIdx.x;
    if (e < N_EDGES) atomicAdd(&deg[dst[e]], 1);
}

__global__ void k_blocksum(const int* __restrict__ deg, int* __restrict__ bsum) {
    __shared__ int sm[4];
    int b = blockIdx.x, t = threadIdx.x;
    int base = b * SCAN_CHUNK;
    int s = 0;
    for (int i = 0; i < 4; ++i) {
        int idx = base + t + i * 256;
        if (idx < N_NODES) s += deg[idx];
    }
    for (int off = 32; off; off >>= 1) s += __shfl_down(s, off);
    if ((t & 63) == 0) sm[t >> 6] = s;
    __syncthreads();
    if (t == 0) bsum[b] = sm[0] + sm[1] + sm[2] + sm[3];
}

__global__ void k_scan_bsum(const int* __restrict__ bsum, int* __restrict__ bscan) {
    if (threadIdx.x == 0) {
        int r = 0;
        for (int i = 0; i < NBLK; ++i) { bscan[i] = r; r += bsum[i]; }
    }
}

__global__ void k_scan_final(const int* __restrict__ deg, const int* __restrict__ bscan,
                             int* __restrict__ offsets, int* __restrict__ cursor) {
    __shared__ int sm[256];
    int b = blockIdx.x, t = threadIdx.x;
    int base = b * SCAN_CHUNK + t * 4;
    int c[4];
    for (int e = 0; e < 4; ++e) {
        int idx = base + e;
        c[e] = (idx < N_NODES) ? deg[idx] : 0;
    }
    int s = c[0] + c[1] + c[2] + c[3];
    sm[t] = s;
    __syncthreads();
    for (int off = 1; off < 256; off <<= 1) {
        int v = (t >= off) ? sm[t - off] : 0;
        __syncthreads();
        sm[t] += v;
        __syncthreads();
    }
    int run = sm[t] - s + bscan[b];
    for (int e = 0; e < 4; ++e) {
        int idx = base + e;
        if (idx < N_NODES) { offsets[idx] = run; cursor[idx] = run; }
        run += c[e];
    }
}

__global__ void k_fill(const int* __restrict__ src, const int* __restrict__ dst,
                       int* __restrict__ cursor, int* __restrict__ csr) {
    int e = blockIdx.x * 256 + threadIdx.x;
    if (e < N_EDGES) {
        int d = dst[e];
        int pos = atomicAdd(&cursor[d], 1);
        csr[pos] = src[e];
    }
}

// ---------------- mean aggregation (wave per node) ----------------
__global__ void k_aggregate(const float* __restrict__ x, const int* __restrict__ offsets,
                            const int* __restrict__ deg, const int* __restrict__ csr,
                            float* __restrict__ agg) {
    int wave = threadIdx.x >> 6;
    int lane = threadIdx.x & 63;
    int node = blockIdx.x * 4 + wave;
    int off = offsets[node];
    int dg = deg[node];
    float4 acc = {0.f, 0.f, 0.f, 0.f};
    for (int j = 0; j < dg; ++j) {
        int s = csr[off + j];
        float4 v = *reinterpret_cast<const float4*>(x + (size_t)s * HID + lane * 4);
        acc.x += v.x; acc.y += v.y; acc.z += v.z; acc.w += v.w;
    }
    float inv = 1.0f / (float)(dg > 0 ? dg : 1);
    acc.x *= inv; acc.y *= inv; acc.z *= inv; acc.w *= inv;
    *reinterpret_cast<float4*>(agg + (size_t)node * HID + lane * 4) = acc;
}

// ---------------- fused fp32 GEMM: C = relu?(bias + A1@B1 [+ A2@B2]) ----------------
// A pitch is always HID(=256) floats; B is [256][BN] row-major; C pitch = BN.
// BN == full N  =>  one column-block per row-tile  =>  in-place C==A2 is safe.
template <int BM, int BN>
__global__ __launch_bounds__(256, 2) void k_gemm(
    const float* __restrict__ A1, const float* __restrict__ B1,
    const float* __restrict__ A2, const float* __restrict__ B2,
    const float* __restrict__ bias, float* __restrict__ C,
    int M, int doRelu) {
    constexpr int BK = 16;
    __shared__ float As[BK][BM];
    __shared__ float Bs[BK][BN];
    const int tid = threadIdx.x;
    const int m0 = blockIdx.x * BM;
    constexpr int TNG = BN / 8;           // thread groups along N
    const int tn = tid % TNG;
    const int tm = tid / TNG;             // 0 .. BM/8-1
    float acc[2][2][4][4] = {};

    for (int srcIdx = 0; srcIdx < 2; ++srcIdx) {
        const float* A = srcIdx ? A2 : A1;
        const float* B = srcIdx ? B2 : B1;
        if (!A) break;
        for (int kk = 0; kk < HID; kk += BK) {
            // A tile: BM x BK, stored transposed As[k][m]
            for (int idx = tid; idx < BM * BK / 4; idx += 256) {
                int row = idx / (BK / 4);
                int c4  = idx % (BK / 4);
                int gm = m0 + row; if (gm > M - 1) gm = M - 1;
                float4 v = *reinterpret_cast<const float4*>(A + (size_t)gm * HID + kk + c4 * 4);
                As[c4 * 4 + 0][row] = v.x;
                As[c4 * 4 + 1][row] = v.y;
                As[c4 * 4 + 2][row] = v.z;
                As[c4 * 4 + 3][row] = v.w;
            }
            // B tile: BK x BN, natural layout
            for (int idx = tid; idx < BK * BN / 4; idx += 256) {
                int krow = idx / (BN / 4);
                int c4   = idx % (BN / 4);
                float4 v = *reinterpret_cast<const float4*>(B + (size_t)(kk + krow) * BN + c4 * 4);
                *reinterpret_cast<float4*>(&Bs[krow][c4 * 4]) = v;
            }
            __syncthreads();
            for (int k = 0; k < BK; ++k) {
                float4 a0 = *reinterpret_cast<const float4*>(&As[k][tm * 4]);
                float4 a1 = *reinterpret_cast<const float4*>(&As[k][tm * 4 + BM / 2]);
                float4 b0 = *reinterpret_cast<const float4*>(&Bs[k][tn * 4]);
                float4 b1 = *reinterpret_cast<const float4*>(&Bs[k][tn * 4 + BN / 2]);
                float av[2][4] = {{a0.x, a0.y, a0.z, a0.w}, {a1.x, a1.y, a1.z, a1.w}};
                float bv[2][4] = {{b0.x, b0.y, b0.z, b0.w}, {b1.x, b1.y, b1.z, b1.w}};
#pragma unroll
                for (int hm = 0; hm < 2; ++hm)
#pragma unroll
                    for (int r = 0; r < 4; ++r)
#pragma unroll
                        for (int hn = 0; hn < 2; ++hn)
#pragma unroll
                            for (int c = 0; c < 4; ++c)
                                acc[hm][hn][r][c] += av[hm][r] * bv[hn][c];
            }
            __syncthreads();
        }
    }

    // epilogue
#pragma unroll
    for (int hm = 0; hm < 2; ++hm)
#pragma unroll
        for (int r = 0; r < 4; ++r) {
            int gm = m0 + tm * 4 + hm * (BM / 2) + r;
            if (gm >= M) continue;
#pragma unroll
            for (int hn = 0; hn < 2; ++hn) {
                int gn = tn * 4 + hn * (BN / 2);
                float4 o;
                o.x = acc[hm][hn][r][0] + bias[gn + 0];
                o.y = acc[hm][hn][r][1] + bias[gn + 1];
                o.z = acc[hm][hn][r][2] + bias[gn + 2];
                o.w = acc[hm][hn][r][3] + bias[gn + 3];
                if (doRelu) {
                    o.x = fmaxf(o.x, 0.f); o.y = fmaxf(o.y, 0.f);
                    o.z = fmaxf(o.z, 0.f); o.w = fmaxf(o.w, 0.f);
                }
                *reinterpret_cast<float4*>(C + (size_t)gm * BN + gn) = o;
            }
        }
}

// ---------------- head: out = h @ W2 + b2   (128 -> 4) ----------------
__global__ void k_head(const float* __restrict__ h, const float* __restrict__ W2,
                       const float* __restrict__ b2, float* __restrict__ out) {
    int wave = threadIdx.x >> 6, lane = threadIdx.x & 63;
    int node = blockIdx.x * 4 + wave;
    const float* hr = h + (size_t)node * 128;
    float p0 = 0.f, p1 = 0.f, p2 = 0.f, p3 = 0.f;
    for (int j = lane; j < 128; j += 64) {
        float hv = hr[j];
        p0 += hv * W2[j * 4 + 0];
        p1 += hv * W2[j * 4 + 1];
        p2 += hv * W2[j * 4 + 2];
        p3 += hv * W2[j * 4 + 3];
    }
    for (int off = 32; off; off >>= 1) {
        p0 += __shfl_down(p0, off);
        p1 += __shfl_down(p1, off);
        p2 += __shfl_down(p2, off);
        p3 += __shfl_down(p3, off);
    }
    if (lane == 0) {
        float4 o = {p0 + b2[0], p1 + b2[1], p2 + b2[2], p3 + b2[3]};
        *reinterpret_cast<float4*>(out + (size_t)node * 4) = o;
    }
}

extern "C" void kernel_launch(void* const* d_in, const int* in_sizes, int n_in,
                              void* d_out, int out_size, void* d_ws, size_t ws_size,
                              hipStream_t stream) {
    const float* x  = (const float*)d_in[0];
    const int*   ei = (const int*)d_in[1];
    const float* Wl = (const float*)d_in[2];
    const float* bl = (const float*)d_in[3];
    const float* Wr = (const float*)d_in[4];
    const float* W1 = (const float*)d_in[5];
    const float* b1 = (const float*)d_in[6];
    const float* W2 = (const float*)d_in[7];
    const float* b2 = (const float*)d_in[8];
    float* out = (float*)d_out;

    char* w = (char*)d_ws;
    size_t o = 0;
    auto alloc = [&](size_t bytes) -> void* {
        void* p = w + o;
        o += (bytes + 255) & ~(size_t)255;
        return p;
    };
    int* deg     = (int*)alloc((size_t)N_NODES * 4);
    int* cursor  = (int*)alloc((size_t)N_NODES * 4);
    int* offsets = (int*)alloc((size_t)N_NODES * 4);
    int* bsum    = (int*)alloc((size_t)NBLK * 4);
    int* bscan   = (int*)alloc((size_t)NBLK * 4);
    int* csr     = (int*)alloc((size_t)N_EDGES * 4);
    float* agg   = (float*)alloc((size_t)N_NODES * HID * 4);
    float* feat  = (float*)alloc((size_t)N_NODES * HID * 4);

    const int* srcA = ei;
    const int* dstA = ei + N_EDGES;

    hipMemsetAsync(deg, 0, (size_t)N_NODES * 4, stream);
    k_count<<<(N_EDGES + 255) / 256, 256, 0, stream>>>(dstA, deg);
    k_blocksum<<<NBLK, 256, 0, stream>>>(deg, bsum);
    k_scan_bsum<<<1, 64, 0, stream>>>(bsum, bscan);
    k_scan_final<<<NBLK, 256, 0, stream>>>(deg, bscan, offsets, cursor);
    k_fill<<<(N_EDGES + 255) / 256, 256, 0, stream>>>(srcA, dstA, cursor, csr);

    const float* xin = x;
    for (int l = 0; l < 3; ++l) {
        k_aggregate<<<N_NODES / 4, 256, 0, stream>>>(xin, offsets, deg, csr, agg);
        k_gemm<64, 256><<<(N_NODES + 63) / 64, 256, 0, stream>>>(
            agg, Wl + (size_t)l * 65536, xin, Wr + (size_t)l * 65536,
            bl + (size_t)l * 256, feat, N_NODES, 1);
        xin = feat;
    }
    float* h = agg;  // reuse
    k_gemm<128, 128><<<(N_NODES + 127) / 128, 256, 0, stream>>>(
        feat, W1, nullptr, nullptr, b1, h, N_NODES, 1);
    k_head<<<N_NODES / 4, 256, 0, stream>>>(h, W2, b2, out);
}

// Round 2
// 1476.925 us; speedup vs baseline: 1.3827x; 1.3827x over previous
//
#include <hip/hip_runtime.h>

#define N_NODES 100000
#define N_EDGES 1600000
#define HID 256

typedef _Float16 half_t;
using f16x8 = __attribute__((ext_vector_type(8))) half_t;
using f32x4 = __attribute__((ext_vector_type(4))) float;

constexpr int SCAN_CHUNK = 1024;
constexpr int NBLK = (N_NODES + SCAN_CHUNK - 1) / SCAN_CHUNK; // 98

#define GLOAD_LDS16(gp, lp)                                                    \
    __builtin_amdgcn_global_load_lds(                                         \
        (const __attribute__((address_space(1))) void*)(gp),                  \
        (__attribute__((address_space(3))) void*)(lp), 16, 0, 0)

// ---------------- CSR build ----------------
__global__ void k_count(const int* __restrict__ dst, int* __restrict__ deg) {
    int e = blockIdx.x * 256 + threadIdx.x;
    if (e < N_EDGES) atomicAdd(&deg[dst[e]], 1);
}

__global__ void k_blocksum(const int* __restrict__ deg, int* __restrict__ bsum) {
    __shared__ int sm[4];
    int b = blockIdx.x, t = threadIdx.x;
    int base = b * SCAN_CHUNK;
    int s = 0;
    for (int i = 0; i < 4; ++i) {
        int idx = base + t + i * 256;
        if (idx < N_NODES) s += deg[idx];
    }
    for (int off = 32; off; off >>= 1) s += __shfl_down(s, off);
    if ((t & 63) == 0) sm[t >> 6] = s;
    __syncthreads();
    if (t == 0) bsum[b] = sm[0] + sm[1] + sm[2] + sm[3];
}

__global__ void k_scan_bsum(const int* __restrict__ bsum, int* __restrict__ bscan) {
    if (threadIdx.x == 0) {
        int r = 0;
        for (int i = 0; i < NBLK; ++i) { bscan[i] = r; r += bsum[i]; }
    }
}

__global__ void k_scan_final(const int* __restrict__ deg, const int* __restrict__ bscan,
                             int* __restrict__ offsets, int* __restrict__ cursor) {
    __shared__ int sm[256];
    int b = blockIdx.x, t = threadIdx.x;
    int base = b * SCAN_CHUNK + t * 4;
    int c[4];
    for (int e = 0; e < 4; ++e) {
        int idx = base + e;
        c[e] = (idx < N_NODES) ? deg[idx] : 0;
    }
    int s = c[0] + c[1] + c[2] + c[3];
    sm[t] = s;
    __syncthreads();
    for (int off = 1; off < 256; off <<= 1) {
        int v = (t >= off) ? sm[t - off] : 0;
        __syncthreads();
        sm[t] += v;
        __syncthreads();
    }
    int run = sm[t] - s + bscan[b];
    for (int e = 0; e < 4; ++e) {
        int idx = base + e;
        if (idx < N_NODES) { offsets[idx] = run; cursor[idx] = run; }
        run += c[e];
    }
}

__global__ void k_fill(const int* __restrict__ src, const int* __restrict__ dst,
                       int* __restrict__ cursor, int* __restrict__ csr) {
    int e = blockIdx.x * 256 + threadIdx.x;
    if (e < N_EDGES) {
        int d = dst[e];
        int pos = atomicAdd(&cursor[d], 1);
        csr[pos] = src[e];
    }
}

// ---------------- mean aggregation (wave per node) ----------------
__global__ void k_aggregate(const float* __restrict__ x, const int* __restrict__ offsets,
                            const int* __restrict__ deg, const int* __restrict__ csr,
                            float* __restrict__ agg) {
    int wave = threadIdx.x >> 6;
    int lane = threadIdx.x & 63;
    int node = blockIdx.x * 4 + wave;
    int off = offsets[node];
    int dg = deg[node];
    float4 acc = {0.f, 0.f, 0.f, 0.f};
    for (int j = 0; j < dg; ++j) {
        int s = csr[off + j];
        float4 v = *reinterpret_cast<const float4*>(x + (size_t)s * HID + lane * 4);
        acc.x += v.x; acc.y += v.y; acc.z += v.z; acc.w += v.w;
    }
    float inv = 1.0f / (float)(dg > 0 ? dg : 1);
    acc.x *= inv; acc.y *= inv; acc.z *= inv; acc.w *= inv;
    *reinterpret_cast<float4*>(agg + (size_t)node * HID + lane * 4) = acc;
}

// ---------------- weight split+transpose: Wt_hi[col][k], Wt_lo appended ----
// W: [256][ncols] fp32 row-major. out: hi region (ncols*256 halves) then lo.
__global__ void k_splitw(const float* __restrict__ W, half_t* __restrict__ out, int ncols) {
    int col = blockIdx.x;
    int k = threadIdx.x; // 256 threads, K = 256
    float v = W[(size_t)k * ncols + col];
    half_t h = (half_t)v;
    out[(size_t)col * 256 + k] = h;
    out[(size_t)ncols * 256 + (size_t)col * 256 + k] = (half_t)(v - (float)h);
}

// ---------------- fp16x3 MFMA GEMM ----------------
// C[M][BN] = relu?(bias + A1@B1 [+ A2@B2]); A fp32 [M][256], split to fp16
// hi/lo on the fly. B pre-split: hi[col][256k] then lo[col][256k] (fp16).
// Block: 512 thr (8 waves, 2Mx4N), tile 128 x BN. Full-width BN => in-place
// C==A2 is race-free (block reads only the rows it writes).
template <int BN>
__global__ __launch_bounds__(512, 4) void k_gemm_mfma(
    const float* __restrict__ A1, const half_t* __restrict__ B1,
    const float* __restrict__ A2, const half_t* __restrict__ B2,
    const float* __restrict__ bias, float* __restrict__ C,
    int M, int doRelu) {
    constexpr int WNW = BN / 4;   // wave tile width
    constexpr int NF = WNW / 16;  // n-fragments per wave
    __shared__ f16x8 sAhi[512];   // [kg(4)][row(128)] chunks of 8 halves
    __shared__ f16x8 sAlo[512];
    __shared__ f16x8 sB[8 * BN];  // hi: [0,4*BN), lo: [4*BN,8*BN); [kg][col]

    const int tid = threadIdx.x;
    const int lane = tid & 63;
    const int m0 = blockIdx.x * 128;
    // staging coords (A): one 8-half chunk per thread
    const int skg = tid >> 7;      // 0..3
    const int srow = tid & 127;
    const int grow = min(m0 + srow, M - 1);
    // fragment coords
    const int l16 = lane & 15, fkg = lane >> 4;
    const int wid = tid >> 6, wm = wid >> 2, wn = wid & 3;
    const int aBase = fkg * 128 + wm * 64 + l16;
    const int bBase = fkg * BN + wn * WNW + l16;

    f32x4 acc[4][NF] = {};

    for (int op = 0; op < 2; ++op) {
        const float* A = op ? A2 : A1;
        const half_t* B = op ? B2 : B1;
        if (!A) break;
        const float* aptr = A + (size_t)grow * 256 + skg * 8;
        float4 f0 = *reinterpret_cast<const float4*>(aptr);
        float4 f1 = *reinterpret_cast<const float4*>(aptr + 4);

        for (int s = 0; s < 8; ++s) {
            const int kk = s * 32;
            __syncthreads();  // previous compute done; LDS free
            // B tiles -> LDS via async direct-to-LDS (linear dest per wave)
#pragma unroll
            for (int b = 0; b < BN / 128; ++b) {
                int c = tid + b * 512;
                int col = c & (BN - 1);
                int ckg = (BN == 256) ? (c >> 8) : (c >> 7);
                const half_t* bh = B + (size_t)col * 256 + kk + ckg * 8;
                GLOAD_LDS16(bh, &sB[c]);
                GLOAD_LDS16(bh + (size_t)BN * 256, &sB[4 * BN + c]);
            }
            // split A chunk and write to LDS
            {
                float fv[8] = {f0.x, f0.y, f0.z, f0.w, f1.x, f1.y, f1.z, f1.w};
                f16x8 hi, lo;
#pragma unroll
                for (int j = 0; j < 8; ++j) {
                    half_t h = (half_t)fv[j];
                    hi[j] = h;
                    lo[j] = (half_t)(fv[j] - (float)h);
                }
                sAhi[tid] = hi;
                sAlo[tid] = lo;
            }
            __syncthreads();  // drains vmcnt (B loads) + lgkm (A writes)
            // prefetch next A chunk (overlaps MFMA)
            if (s < 7) {
                f0 = *reinterpret_cast<const float4*>(aptr + (s + 1) * 32);
                f1 = *reinterpret_cast<const float4*>(aptr + (s + 1) * 32 + 4);
            }
            // compute
            f16x8 ah[4], al[4];
#pragma unroll
            for (int mf = 0; mf < 4; ++mf) {
                ah[mf] = sAhi[aBase + mf * 16];
                al[mf] = sAlo[aBase + mf * 16];
            }
#pragma unroll
            for (int nf = 0; nf < NF; ++nf) {
                f16x8 bh = sB[bBase + nf * 16];
                f16x8 bl = sB[4 * BN + bBase + nf * 16];
#pragma unroll
                for (int mf = 0; mf < 4; ++mf) {
                    acc[mf][nf] = __builtin_amdgcn_mfma_f32_16x16x32_f16(ah[mf], bh, acc[mf][nf], 0, 0, 0);
                    acc[mf][nf] = __builtin_amdgcn_mfma_f32_16x16x32_f16(al[mf], bh, acc[mf][nf], 0, 0, 0);
                    acc[mf][nf] = __builtin_amdgcn_mfma_f32_16x16x32_f16(ah[mf], bl, acc[mf][nf], 0, 0, 0);
                }
            }
        }
    }

    // epilogue: C row = wm*64+mf*16+(lane>>4)*4+r, col = wn*WNW+nf*16+(lane&15)
#pragma unroll
    for (int mf = 0; mf < 4; ++mf) {
        int row = m0 + wm * 64 + mf * 16 + (lane >> 4) * 4;
#pragma unroll
        for (int nf = 0; nf < NF; ++nf) {
            int col = wn * WNW + nf * 16 + l16;
            float bv = bias[col];
#pragma unroll
            for (int r = 0; r < 4; ++r) {
                int gr = row + r;
                if (gr < M) {
                    float v = acc[mf][nf][r] + bv;
                    if (doRelu) v = fmaxf(v, 0.f);
                    C[(size_t)gr * BN + col] = v;
                }
            }
        }
    }
}

// ---------------- head: out = h @ W2 + b2   (128 -> 4) ----------------
__global__ void k_head(const float* __restrict__ h, const float* __restrict__ W2,
                       const float* __restrict__ b2, float* __restrict__ out) {
    int wave = threadIdx.x >> 6, lane = threadIdx.x & 63;
    int node = blockIdx.x * 4 + wave;
    const float* hr = h + (size_t)node * 128;
    float p0 = 0.f, p1 = 0.f, p2 = 0.f, p3 = 0.f;
    for (int j = lane; j < 128; j += 64) {
        float hv = hr[j];
        p0 += hv * W2[j * 4 + 0];
        p1 += hv * W2[j * 4 + 1];
        p2 += hv * W2[j * 4 + 2];
        p3 += hv * W2[j * 4 + 3];
    }
    for (int off = 32; off; off >>= 1) {
        p0 += __shfl_down(p0, off);
        p1 += __shfl_down(p1, off);
        p2 += __shfl_down(p2, off);
        p3 += __shfl_down(p3, off);
    }
    if (lane == 0) {
        float4 o = {p0 + b2[0], p1 + b2[1], p2 + b2[2], p3 + b2[3]};
        *reinterpret_cast<float4*>(out + (size_t)node * 4) = o;
    }
}

extern "C" void kernel_launch(void* const* d_in, const int* in_sizes, int n_in,
                              void* d_out, int out_size, void* d_ws, size_t ws_size,
                              hipStream_t stream) {
    const float* x  = (const float*)d_in[0];
    const int*   ei = (const int*)d_in[1];
    const float* Wl = (const float*)d_in[2];
    const float* bl = (const float*)d_in[3];
    const float* Wr = (const float*)d_in[4];
    const float* W1 = (const float*)d_in[5];
    const float* b1 = (const float*)d_in[6];
    const float* W2 = (const float*)d_in[7];
    const float* b2 = (const float*)d_in[8];
    float* out = (float*)d_out;

    char* w = (char*)d_ws;
    size_t o = 0;
    auto alloc = [&](size_t bytes) -> void* {
        void* p = w + o;
        o += (bytes + 255) & ~(size_t)255;
        return p;
    };
    int* deg     = (int*)alloc((size_t)N_NODES * 4);
    int* cursor  = (int*)alloc((size_t)N_NODES * 4);
    int* offsets = (int*)alloc((size_t)N_NODES * 4);
    int* bsum    = (int*)alloc((size_t)NBLK * 4);
    int* bscan   = (int*)alloc((size_t)NBLK * 4);
    int* csr     = (int*)alloc((size_t)N_EDGES * 4);
    float* agg   = (float*)alloc((size_t)N_NODES * HID * 4);
    float* feat  = (float*)alloc((size_t)N_NODES * HID * 4);
    // pre-split transposed weights (fp16 hi|lo)
    half_t* WlT[3]; half_t* WrT[3];
    for (int l = 0; l < 3; ++l) {
        WlT[l] = (half_t*)alloc((size_t)256 * 256 * 2 * 2);
        WrT[l] = (half_t*)alloc((size_t)256 * 256 * 2 * 2);
    }
    half_t* W1T = (half_t*)alloc((size_t)128 * 256 * 2 * 2);
    float* h = agg;  // reuse agg region for MLP hidden (GEMM reads feat only)

    const int* srcA = ei;
    const int* dstA = ei + N_EDGES;

    // weight splits (independent; launch first)
    for (int l = 0; l < 3; ++l) {
        k_splitw<<<256, 256, 0, stream>>>(Wl + (size_t)l * 65536, WlT[l], 256);
        k_splitw<<<256, 256, 0, stream>>>(Wr + (size_t)l * 65536, WrT[l], 256);
    }
    k_splitw<<<128, 256, 0, stream>>>(W1, W1T, 128);

    // CSR build
    hipMemsetAsync(deg, 0, (size_t)N_NODES * 4, stream);
    k_count<<<(N_EDGES + 255) / 256, 256, 0, stream>>>(dstA, deg);
    k_blocksum<<<NBLK, 256, 0, stream>>>(deg, bsum);
    k_scan_bsum<<<1, 64, 0, stream>>>(bsum, bscan);
    k_scan_final<<<NBLK, 256, 0, stream>>>(deg, bscan, offsets, cursor);
    k_fill<<<(N_EDGES + 255) / 256, 256, 0, stream>>>(srcA, dstA, cursor, csr);

    const int mblocks = (N_NODES + 127) / 128;
    const float* xin = x;
    for (int l = 0; l < 3; ++l) {
        k_aggregate<<<N_NODES / 4, 256, 0, stream>>>(xin, offsets, deg, csr, agg);
        k_gemm_mfma<256><<<mblocks, 512, 0, stream>>>(
            agg, WlT[l], xin, WrT[l], bl + (size_t)l * 256, feat, N_NODES, 1);
        xin = feat;
    }
    k_gemm_mfma<128><<<mblocks, 512, 0, stream>>>(
        feat, W1T, nullptr, nullptr, b1, h, N_NODES, 1);
    k_head<<<N_NODES / 4, 256, 0, stream>>>(h, W2, b2, out);
}